// Round 1
// baseline (815.668 us; speedup 1.0000x reference)
//
#include <hip/hip_runtime.h>
#include <hip/hip_bf16.h>

#define N_NODES 100000
#define N_EDGES 3200000
#define NBLK_SCAN 98         // ceil(100000 / 1024)

typedef short v8s __attribute__((ext_vector_type(8)));
typedef float v4f __attribute__((ext_vector_type(4)));

__device__ __forceinline__ unsigned short f2b(float x) {
    __hip_bfloat16 h = __float2bfloat16(x);
    return *reinterpret_cast<unsigned short*>(&h);
}
__device__ __forceinline__ float b2f(unsigned short u) {
    return __uint_as_float(((unsigned int)u) << 16);
}

// async global->LDS, 16B per lane. LDS dest is wave-uniform base + lane*16,
// so LDS layout must be slot-contiguous in lane order (we XOR-swizzle the
// GLOBAL side instead, since the LDS side can't be padded).
__device__ __forceinline__ void gld16(const void* g, void* l) {
    __builtin_amdgcn_global_load_lds(
        (const __attribute__((address_space(1))) void*)g,
        (__attribute__((address_space(3))) void*)l, 16, 0, 0);
}

// ---------------------------------------------------------------------------
// Pre-transpose + convert weight: B[k][n] fp32 -> BT[n][k] bf16
// ---------------------------------------------------------------------------
__global__ void transpose_b(const float* __restrict__ B, unsigned short* __restrict__ BT) {
    int n = blockIdx.x;
    int k = threadIdx.x;
    BT[n * 256 + k] = f2b(B[k * 256 + n]);
}

// ---------------------------------------------------------------------------
// GEMM (m97-style): 128x256 tile, 512 threads (8 waves x 16 rows), BK=64,
// global_load_lds(16B) staging for A (fp32, cvt at frag read) and B (bf16).
// XOR-swizzled chunk layouts -> 2-way max LDS bank aliasing (free).
// ---------------------------------------------------------------------------
__global__ __launch_bounds__(512)
void gemm_dma(const float* __restrict__ A, const unsigned short* __restrict__ BT,
              unsigned short* __restrict__ C) {
    __shared__ __align__(16) float          sA[128 * 64];   // 32 KB
    __shared__ __align__(16) unsigned short sB[256 * 64];   // 32 KB

    const int tid  = threadIdx.x;
    const int wave = tid >> 6;
    const int lane = tid & 63;
    const int quad = lane >> 4;
    const int l16  = lane & 15;
    const int row0 = blockIdx.x * 128;

    v4f acc[16];
#pragma unroll
    for (int t = 0; t < 16; t++) acc[t] = (v4f){0.f, 0.f, 0.f, 0.f};

    const int ml = wave * 16 + l16;            // this lane's A row (local)

    for (int ks = 0; ks < 4; ks++) {
        const int kbase = ks * 64;
        // --- stage A: 128 x 64 fp32 = 2048 x 16B chunks ---
#pragma unroll
        for (int i = 0; i < 4; i++) {
            int s = i * 512 + tid;
            int m = s >> 4;
            int c = (s & 15) ^ (m & 15);
            int row = row0 + m;
            if (row >= N_NODES) row = row0;    // clamp (stores are guarded)
            gld16(A + (size_t)row * 256 + kbase + c * 4, (char*)sA + (size_t)s * 16);
        }
        // --- stage B: 256 x 64 bf16 = 2048 x 16B chunks ---
#pragma unroll
        for (int i = 0; i < 4; i++) {
            int s = i * 512 + tid;
            int n = s >> 3;
            int c = (s & 7) ^ (n & 7);
            gld16(BT + (size_t)n * 256 + kbase + c * 8, (char*)sB + (size_t)s * 16);
        }
        __syncthreads();

#pragma unroll
        for (int sub = 0; sub < 2; sub++) {
            int ca  = sub * 8 + 2 * quad;
            int pa0 = ml * 16 + (ca ^ (ml & 15));
            int pa1 = ml * 16 + ((ca + 1) ^ (ml & 15));
            v4f lo = *(const v4f*)&sA[pa0 * 4];
            v4f hi = *(const v4f*)&sA[pa1 * 4];
            v8s af;
            af[0] = (short)f2b(lo[0]); af[1] = (short)f2b(lo[1]);
            af[2] = (short)f2b(lo[2]); af[3] = (short)f2b(lo[3]);
            af[4] = (short)f2b(hi[0]); af[5] = (short)f2b(hi[1]);
            af[6] = (short)f2b(hi[2]); af[7] = (short)f2b(hi[3]);
            int cb = sub * 4 + quad;
#pragma unroll
            for (int t = 0; t < 16; t++) {
                int n  = t * 16 + l16;
                int pb = n * 8 + (cb ^ (n & 7));
                v8s bf = *(const v8s*)&sB[pb * 8];
                acc[t] = __builtin_amdgcn_mfma_f32_16x16x32_bf16(af, bf, acc[t], 0, 0, 0);
            }
        }
        __syncthreads();
    }

    // epilogue: D mapping col = l16, row = quad*4 + reg
    const int grow_base = row0 + wave * 16 + quad * 4;
#pragma unroll
    for (int t = 0; t < 16; t++) {
#pragma unroll
        for (int r = 0; r < 4; r++) {
            int grow = grow_base + r;
            if (grow < N_NODES)
                C[(size_t)grow * 256 + t * 16 + l16] = f2b(acc[t][r]);
        }
    }
}

// ---------------------------------------------------------------------------
// Per-row histogram: 3.2M global atomics into 400 KB (L2-resident).
// ---------------------------------------------------------------------------
__global__ __launch_bounds__(256)
void hist_kernel(const int* __restrict__ row, int* __restrict__ counts) {
    const int e0 = blockIdx.x * 4096 + threadIdx.x;
#pragma unroll
    for (int j = 0; j < 16; j++) {
        int e = e0 + j * 256;
        if (e < N_EDGES) atomicAdd(&counts[row[e]], 1);
    }
}

// ---------------------------------------------------------------------------
// Two-level exclusive scan of counts[100000] -> offs, block sums -> bsum.
// ---------------------------------------------------------------------------
__global__ __launch_bounds__(1024)
void scan1_kernel(const int* __restrict__ counts, int* __restrict__ offs,
                  int* __restrict__ bsum) {
    __shared__ int s[1024];
    const int tid = threadIdx.x;
    const int i = blockIdx.x * 1024 + tid;
    int x = (i < N_NODES) ? counts[i] : 0;
    s[tid] = x;
    __syncthreads();
    for (int off = 1; off < 1024; off <<= 1) {
        int v = (tid >= off) ? s[tid - off] : 0;
        __syncthreads();
        s[tid] += v;
        __syncthreads();
    }
    if (i < N_NODES) offs[i] = s[tid] - x;      // block-local exclusive
    if (tid == 1023) bsum[blockIdx.x] = s[1023];
}

__global__ void scan2_kernel(int* __restrict__ bsum) {
    __shared__ int s[128];
    const int tid = threadIdx.x;                // 128 threads
    int x = (tid < NBLK_SCAN) ? bsum[tid] : 0;
    s[tid] = x;
    __syncthreads();
    for (int off = 1; off < 128; off <<= 1) {
        int v = (tid >= off) ? s[tid - off] : 0;
        __syncthreads();
        s[tid] += v;
        __syncthreads();
    }
    if (tid < NBLK_SCAN) bsum[tid] = s[tid] - x; // exclusive block prefix
}

__global__ __launch_bounds__(256)
void fixup_kernel(int* __restrict__ offs, const int* __restrict__ bsum,
                  int* __restrict__ cur) {
    const int i = blockIdx.x * 256 + threadIdx.x;
    if (i < N_NODES) {
        int o = offs[i] + bsum[i >> 10];
        offs[i] = o;
        cur[i]  = o;
    }
}

// ---------------------------------------------------------------------------
// Direct scatter to final CSR position (replaces bin + counting sort).
// Entry: 4B packed = (bf16-val-sans-sign << 17) | col  (col < 2^17).
// ---------------------------------------------------------------------------
__global__ __launch_bounds__(256)
void scatter_kernel(const int* __restrict__ row, const int* __restrict__ col,
                    const float* __restrict__ val, int* __restrict__ cur,
                    unsigned int* __restrict__ csr) {
    const int e0 = blockIdx.x * 4096 + threadIdx.x;
#pragma unroll
    for (int j = 0; j < 16; j++) {
        int e = e0 + j * 256;
        if (e < N_EDGES) {
            int r = row[e];
            int p = atomicAdd(&cur[r], 1);
            unsigned int vb = (((unsigned int)__float_as_int(val[e]) + 0x8000u) >> 16) & 0x7FFFu;
            csr[p] = (vb << 17) | (unsigned int)col[e];
        }
    }
}

// ---------------------------------------------------------------------------
// SpMM: one wave per row, j-loop unrolled x8 -> 8 gathers in flight.
// ---------------------------------------------------------------------------
__global__ __launch_bounds__(256)
void spmm_kernel(const unsigned short* __restrict__ sup,
                 const int* __restrict__ offs, const int* __restrict__ counts,
                 const unsigned int* __restrict__ csr, float* __restrict__ out) {
    const int wave = threadIdx.x >> 6;
    const int lane = threadIdx.x & 63;
    const int row  = blockIdx.x * 4 + wave;
    if (row >= N_NODES) return;

    const int start = offs[row];
    const int deg   = counts[row];

    float a0 = 0.f, a1 = 0.f, a2 = 0.f, a3 = 0.f;

    for (int base = 0; base < deg; base += 64) {
        int nb = deg - base;
        if (nb > 64) nb = 64;
        int c = 0;
        float v = 0.f;
        if (lane < nb) {
            unsigned int w = csr[start + base + lane];
            c = (int)(w & 0x1FFFFu);
            v = __uint_as_float((w >> 17) << 16);
        }
        int j = 0;
        for (; j + 8 <= nb; j += 8) {
            int   cc[8];
            float vv[8];
#pragma unroll
            for (int u = 0; u < 8; u++) { cc[u] = __shfl(c, j + u); vv[u] = __shfl(v, j + u); }
            ushort4 h[8];
#pragma unroll
            for (int u = 0; u < 8; u++)
                h[u] = *(const ushort4*)(sup + (size_t)cc[u] * 256 + lane * 4);
#pragma unroll
            for (int u = 0; u < 8; u++) {
                a0 += vv[u] * b2f(h[u].x); a1 += vv[u] * b2f(h[u].y);
                a2 += vv[u] * b2f(h[u].z); a3 += vv[u] * b2f(h[u].w);
            }
        }
        for (; j + 4 <= nb; j += 4) {
            int   c0 = __shfl(c, j),     c1 = __shfl(c, j + 1);
            int   c2 = __shfl(c, j + 2), c3 = __shfl(c, j + 3);
            float v0 = __shfl(v, j),     v1 = __shfl(v, j + 1);
            float v2 = __shfl(v, j + 2), v3 = __shfl(v, j + 3);
            ushort4 h0 = *(const ushort4*)(sup + (size_t)c0 * 256 + lane * 4);
            ushort4 h1 = *(const ushort4*)(sup + (size_t)c1 * 256 + lane * 4);
            ushort4 h2 = *(const ushort4*)(sup + (size_t)c2 * 256 + lane * 4);
            ushort4 h3 = *(const ushort4*)(sup + (size_t)c3 * 256 + lane * 4);
            a0 += v0 * b2f(h0.x); a1 += v0 * b2f(h0.y);
            a2 += v0 * b2f(h0.z); a3 += v0 * b2f(h0.w);
            a0 += v1 * b2f(h1.x); a1 += v1 * b2f(h1.y);
            a2 += v1 * b2f(h1.z); a3 += v1 * b2f(h1.w);
            a0 += v2 * b2f(h2.x); a1 += v2 * b2f(h2.y);
            a2 += v2 * b2f(h2.z); a3 += v2 * b2f(h2.w);
            a0 += v3 * b2f(h3.x); a1 += v3 * b2f(h3.y);
            a2 += v3 * b2f(h3.z); a3 += v3 * b2f(h3.w);
        }
        for (; j < nb; j++) {
            int   cj = __shfl(c, j);
            float vj = __shfl(v, j);
            ushort4 hh = *(const ushort4*)(sup + (size_t)cj * 256 + lane * 4);
            a0 += vj * b2f(hh.x); a1 += vj * b2f(hh.y);
            a2 += vj * b2f(hh.z); a3 += vj * b2f(hh.w);
        }
    }

    float4 o;
    o.x = a0 > 0.f ? a0 : 0.f;
    o.y = a1 > 0.f ? a1 : 0.f;
    o.z = a2 > 0.f ? a2 : 0.f;
    o.w = a3 > 0.f ? a3 : 0.f;
    *(float4*)(out + (size_t)row * 256 + lane * 4) = o;
}

// ---------------------------------------------------------------------------
extern "C" void kernel_launch(void* const* d_in, const int* in_sizes, int n_in,
                              void* d_out, int out_size, void* d_ws, size_t ws_size,
                              hipStream_t stream) {
    const float* features = (const float*)d_in[0];
    const float* weight   = (const float*)d_in[1];
    const int*   adj_row  = (const int*)d_in[2];
    const int*   adj_col  = (const int*)d_in[3];
    const float* adj_val  = (const float*)d_in[4];
    float* out = (float*)d_out;

    char* ws = (char*)d_ws;
    size_t off = 0;
    auto alloc = [&](size_t bytes) -> char* {
        char* p = ws + off;
        off = (off + bytes + 255) & ~(size_t)255;
        return p;
    };
    unsigned short* sup     = (unsigned short*)alloc((size_t)N_NODES * 256 * 2); // 51.2 MB
    unsigned short* BT      = (unsigned short*)alloc(256 * 256 * 2);
    int*            counts  = (int*)alloc((size_t)N_NODES * 4);
    int*            offsets = (int*)alloc((size_t)N_NODES * 4);
    int*            cur     = (int*)alloc((size_t)N_NODES * 4);
    int*            bsum    = (int*)alloc(512 * 4);
    unsigned int*   csr     = (unsigned int*)alloc((size_t)N_EDGES * 4);         // 12.8 MB

    hipMemsetAsync(counts, 0, (size_t)N_NODES * 4, stream);

    transpose_b<<<256, 256, 0, stream>>>(weight, BT);
    gemm_dma<<<782, 512, 0, stream>>>(features, BT, sup);            // ceil(100000/128)
    hist_kernel<<<782, 256, 0, stream>>>(adj_row, counts);           // ceil(3.2M/4096)
    scan1_kernel<<<NBLK_SCAN, 1024, 0, stream>>>(counts, offsets, bsum);
    scan2_kernel<<<1, 128, 0, stream>>>(bsum);
    fixup_kernel<<<391, 256, 0, stream>>>(offsets, bsum, cur);       // ceil(100000/256)
    scatter_kernel<<<782, 256, 0, stream>>>(adj_row, adj_col, adj_val, cur, csr);
    spmm_kernel<<<25000, 256, 0, stream>>>(sup, offsets, counts, csr, out);
}

// Round 2
// 511.040 us; speedup vs baseline: 1.5961x; 1.5961x over previous
//
#include <hip/hip_runtime.h>
#include <hip/hip_bf16.h>

#define N_NODES 100000
#define N_EDGES 3200000
#define NBUCK   391          // ceil(100000 / 256) buckets of 256 rows

typedef short v8s __attribute__((ext_vector_type(8)));
typedef float v4f __attribute__((ext_vector_type(4)));

__device__ __forceinline__ unsigned short f2b(float x) {
    __hip_bfloat16 h = __float2bfloat16(x);
    return *reinterpret_cast<unsigned short*>(&h);
}
__device__ __forceinline__ float b2f(unsigned short u) {
    return __uint_as_float(((unsigned int)u) << 16);
}

// async global->LDS, 16B per lane.
__device__ __forceinline__ void gld16(const void* g, void* l) {
    __builtin_amdgcn_global_load_lds(
        (const __attribute__((address_space(1))) void*)g,
        (__attribute__((address_space(3))) void*)l, 16, 0, 0);
}

// ---------------------------------------------------------------------------
// Pre-transpose + convert weight: B[k][n] fp32 -> BT[n][k] bf16
// ---------------------------------------------------------------------------
__global__ void transpose_b(const float* __restrict__ B, unsigned short* __restrict__ BT) {
    int n = blockIdx.x;
    int k = threadIdx.x;
    BT[n * 256 + k] = f2b(B[k * 256 + n]);
}

// ---------------------------------------------------------------------------
// GEMM (m97-style): 128x256 tile, 512 threads, BK=64, global_load_lds(16B).
// ---------------------------------------------------------------------------
__global__ __launch_bounds__(512)
void gemm_dma(const float* __restrict__ A, const unsigned short* __restrict__ BT,
              unsigned short* __restrict__ C) {
    __shared__ __align__(16) float          sA[128 * 64];   // 32 KB
    __shared__ __align__(16) unsigned short sB[256 * 64];   // 32 KB

    const int tid  = threadIdx.x;
    const int wave = tid >> 6;
    const int lane = tid & 63;
    const int quad = lane >> 4;
    const int l16  = lane & 15;
    const int row0 = blockIdx.x * 128;

    v4f acc[16];
#pragma unroll
    for (int t = 0; t < 16; t++) acc[t] = (v4f){0.f, 0.f, 0.f, 0.f};

    const int ml = wave * 16 + l16;

    for (int ks = 0; ks < 4; ks++) {
        const int kbase = ks * 64;
#pragma unroll
        for (int i = 0; i < 4; i++) {
            int s = i * 512 + tid;
            int m = s >> 4;
            int c = (s & 15) ^ (m & 15);
            int row = row0 + m;
            if (row >= N_NODES) row = row0;
            gld16(A + (size_t)row * 256 + kbase + c * 4, (char*)sA + (size_t)s * 16);
        }
#pragma unroll
        for (int i = 0; i < 4; i++) {
            int s = i * 512 + tid;
            int n = s >> 3;
            int c = (s & 7) ^ (n & 7);
            gld16(BT + (size_t)n * 256 + kbase + c * 8, (char*)sB + (size_t)s * 16);
        }
        __syncthreads();

#pragma unroll
        for (int sub = 0; sub < 2; sub++) {
            int ca  = sub * 8 + 2 * quad;
            int pa0 = ml * 16 + (ca ^ (ml & 15));
            int pa1 = ml * 16 + ((ca + 1) ^ (ml & 15));
            v4f lo = *(const v4f*)&sA[pa0 * 4];
            v4f hi = *(const v4f*)&sA[pa1 * 4];
            v8s af;
            af[0] = (short)f2b(lo[0]); af[1] = (short)f2b(lo[1]);
            af[2] = (short)f2b(lo[2]); af[3] = (short)f2b(lo[3]);
            af[4] = (short)f2b(hi[0]); af[5] = (short)f2b(hi[1]);
            af[6] = (short)f2b(hi[2]); af[7] = (short)f2b(hi[3]);
            int cb = sub * 4 + quad;
#pragma unroll
            for (int t = 0; t < 16; t++) {
                int n  = t * 16 + l16;
                int pb = n * 8 + (cb ^ (n & 7));
                v8s bf = *(const v8s*)&sB[pb * 8];
                acc[t] = __builtin_amdgcn_mfma_f32_16x16x32_bf16(af, bf, acc[t], 0, 0, 0);
            }
        }
        __syncthreads();
    }

    const int grow_base = row0 + wave * 16 + quad * 4;
#pragma unroll
    for (int t = 0; t < 16; t++) {
#pragma unroll
        for (int r = 0; r < 4; r++) {
            int grow = grow_base + r;
            if (grow < N_NODES)
                C[(size_t)grow * 256 + t * 16 + l16] = f2b(acc[t][r]);
        }
    }
}

// ---------------------------------------------------------------------------
// Coarse histogram over 391 buckets with LDS pre-aggregation (NO per-edge
// device atomics: ~306K aggregated global atomics total).
// ---------------------------------------------------------------------------
__global__ __launch_bounds__(256)
void bhist_kernel(const int* __restrict__ row, int* __restrict__ ghist) {
    __shared__ int h[NBUCK];
    const int tid = threadIdx.x;
    for (int i = tid; i < NBUCK; i += 256) h[i] = 0;
    __syncthreads();
    const int e0 = blockIdx.x * 4096;
#pragma unroll
    for (int j = 0; j < 16; j++) {
        int e = e0 + j * 256 + tid;
        if (e < N_EDGES) atomicAdd(&h[row[e] >> 8], 1);
    }
    __syncthreads();
    for (int i = tid; i < NBUCK; i += 256)
        if (h[i]) atomicAdd(&ghist[i], h[i]);
}

// Exclusive scan of 391 bucket counts; also initializes the global cursors.
__global__ void bscan_kernel(const int* __restrict__ ghist, int* __restrict__ bbase,
                             int* __restrict__ gcur) {
    __shared__ int s[512];
    const int tid = threadIdx.x;   // 512 threads
    int x = (tid < NBUCK) ? ghist[tid] : 0;
    s[tid] = x;
    __syncthreads();
    for (int off = 1; off < 512; off <<= 1) {
        int v = (tid >= off) ? s[tid - off] : 0;
        __syncthreads();
        s[tid] += v;
        __syncthreads();
    }
    if (tid < NBUCK) {
        int b = s[tid] - x;
        bbase[tid] = b;
        gcur[tid]  = b;
    }
}

// ---------------------------------------------------------------------------
// Bin pass v2: LDS counting-sort of the block's 4096 edges by bucket, then
// copy-out where CONSECUTIVE THREADS write CONSECUTIVE ADDRESSES within each
// bucket run (~306K contiguous runs of ~84B instead of 3.2M scattered 8B).
// Entry: .x = (row_local<<20)|col, .y = fp32 val bits.
// ---------------------------------------------------------------------------
__global__ __launch_bounds__(512)
void bin2_kernel(const int* __restrict__ row, const int* __restrict__ col,
                 const float* __restrict__ val, int* __restrict__ gcur,
                 int2* __restrict__ bucket) {
    __shared__ int  cnt[512];
    __shared__ int  ls[512];     // exclusive local offset per bucket
    __shared__ int  gb[512];     // global base per bucket for this block
    __shared__ int  lcur[512];   // running cursor per bucket
    __shared__ __align__(16) int2 stage[4096];   // 32 KB
    __shared__ int  gdst[4096];                  // 16 KB

    const int tid = threadIdx.x;
    const int e0  = blockIdx.x * 4096;

    int r[8], c[8];
    float v[8];
#pragma unroll
    for (int j = 0; j < 8; j++) {
        int e = e0 + j * 512 + tid;
        if (e < N_EDGES) { r[j] = row[e]; c[j] = col[e]; v[j] = val[e]; }
        else r[j] = -1;
    }

    cnt[tid] = 0;
    __syncthreads();
#pragma unroll
    for (int j = 0; j < 8; j++)
        if (r[j] >= 0) atomicAdd(&cnt[r[j] >> 8], 1);
    __syncthreads();

    int x = cnt[tid];
    // reserve this block's global range for bucket `tid` (aggregated atomic)
    int gbase = 0;
    if (x) gbase = atomicAdd(&gcur[tid], x);
    gb[tid] = gbase;

    // exclusive scan of cnt over 512 slots (Hillis-Steele)
    lcur[tid] = x;
    __syncthreads();
    for (int off = 1; off < 512; off <<= 1) {
        int t = (tid >= off) ? lcur[tid - off] : 0;
        __syncthreads();
        lcur[tid] += t;
        __syncthreads();
    }
    int excl = lcur[tid] - x;
    __syncthreads();
    ls[tid]   = excl;
    lcur[tid] = excl;
    __syncthreads();

    // place edges into LDS stage, record final global destination
#pragma unroll
    for (int j = 0; j < 8; j++) {
        if (r[j] >= 0) {
            int b = r[j] >> 8;
            int q = atomicAdd(&lcur[b], 1);
            stage[q] = make_int2(((r[j] & 255) << 20) | c[j], __float_as_int(v[j]));
            gdst[q]  = gb[b] + (q - ls[b]);
        }
    }
    __syncthreads();

    // copy-out: consecutive i -> consecutive addresses within runs
    int tot = N_EDGES - e0;
    if (tot > 4096) tot = 4096;
    for (int i = tid; i < tot; i += 512)
        bucket[gdst[i]] = stage[i];
}

// ---------------------------------------------------------------------------
// Per-bucket counting sort into final CSR (4B packed) + offs/counts.
// Writes land in this bucket's 32KB csr window (L2-resident, fully dirtied).
// ---------------------------------------------------------------------------
__global__ __launch_bounds__(512)
void csort_kernel(const int2* __restrict__ bucket, const int* __restrict__ bbase,
                  const int* __restrict__ gcur, unsigned int* __restrict__ csr,
                  int* __restrict__ offs, int* __restrict__ counts) {
    __shared__ int h[256];
    __shared__ int s[512];
    __shared__ int cur[256];
    const int tid  = threadIdx.x;         // 512 threads
    const int b    = blockIdx.x;
    const int base = bbase[b];
    const int end  = gcur[b];             // after bin pass: base + bucket size

    if (tid < 256) h[tid] = 0;
    __syncthreads();
    for (int i = base + tid; i < end; i += 512)
        atomicAdd(&h[bucket[i].x >> 20], 1);
    __syncthreads();

    int x = (tid < 256) ? h[tid] : 0;
    s[tid] = x;
    __syncthreads();
    for (int off = 1; off < 512; off <<= 1) {
        int v2 = (tid >= off) ? s[tid - off] : 0;
        __syncthreads();
        s[tid] += v2;
        __syncthreads();
    }
    if (tid < 256) {
        int ro = s[tid] - x;              // exclusive offset within bucket
        int grow = b * 256 + tid;
        if (grow < N_NODES) {
            offs[grow]   = base + ro;
            counts[grow] = x;
        }
        cur[tid] = base + ro;
    }
    __syncthreads();

    for (int i = base + tid; i < end; i += 512) {
        int2 w = bucket[i];
        int rl = w.x >> 20;
        int p  = atomicAdd(&cur[rl], 1);
        unsigned int vb = (((unsigned int)w.y + 0x8000u) >> 16) & 0x7FFFu;
        csr[p] = (vb << 17) | (unsigned int)(w.x & 0x1FFFF);
    }
}

// ---------------------------------------------------------------------------
// SpMM: one wave per row, j-loop unrolled x8 -> 8 gathers in flight.
// ---------------------------------------------------------------------------
__global__ __launch_bounds__(256)
void spmm_kernel(const unsigned short* __restrict__ sup,
                 const int* __restrict__ offs, const int* __restrict__ counts,
                 const unsigned int* __restrict__ csr, float* __restrict__ out) {
    const int wave = threadIdx.x >> 6;
    const int lane = threadIdx.x & 63;
    const int row  = blockIdx.x * 4 + wave;
    if (row >= N_NODES) return;

    const int start = offs[row];
    const int deg   = counts[row];

    float a0 = 0.f, a1 = 0.f, a2 = 0.f, a3 = 0.f;

    for (int base = 0; base < deg; base += 64) {
        int nb = deg - base;
        if (nb > 64) nb = 64;
        int c = 0;
        float v = 0.f;
        if (lane < nb) {
            unsigned int w = csr[start + base + lane];
            c = (int)(w & 0x1FFFFu);
            v = __uint_as_float((w >> 17) << 16);
        }
        int j = 0;
        for (; j + 8 <= nb; j += 8) {
            int   cc[8];
            float vv[8];
#pragma unroll
            for (int u = 0; u < 8; u++) { cc[u] = __shfl(c, j + u); vv[u] = __shfl(v, j + u); }
            ushort4 h[8];
#pragma unroll
            for (int u = 0; u < 8; u++)
                h[u] = *(const ushort4*)(sup + (size_t)cc[u] * 256 + lane * 4);
#pragma unroll
            for (int u = 0; u < 8; u++) {
                a0 += vv[u] * b2f(h[u].x); a1 += vv[u] * b2f(h[u].y);
                a2 += vv[u] * b2f(h[u].z); a3 += vv[u] * b2f(h[u].w);
            }
        }
        for (; j + 4 <= nb; j += 4) {
            int   c0 = __shfl(c, j),     c1 = __shfl(c, j + 1);
            int   c2 = __shfl(c, j + 2), c3 = __shfl(c, j + 3);
            float v0 = __shfl(v, j),     v1 = __shfl(v, j + 1);
            float v2 = __shfl(v, j + 2), v3 = __shfl(v, j + 3);
            ushort4 h0 = *(const ushort4*)(sup + (size_t)c0 * 256 + lane * 4);
            ushort4 h1 = *(const ushort4*)(sup + (size_t)c1 * 256 + lane * 4);
            ushort4 h2 = *(const ushort4*)(sup + (size_t)c2 * 256 + lane * 4);
            ushort4 h3 = *(const ushort4*)(sup + (size_t)c3 * 256 + lane * 4);
            a0 += v0 * b2f(h0.x); a1 += v0 * b2f(h0.y);
            a2 += v0 * b2f(h0.z); a3 += v0 * b2f(h0.w);
            a0 += v1 * b2f(h1.x); a1 += v1 * b2f(h1.y);
            a2 += v1 * b2f(h1.z); a3 += v1 * b2f(h1.w);
            a0 += v2 * b2f(h2.x); a1 += v2 * b2f(h2.y);
            a2 += v2 * b2f(h2.z); a3 += v2 * b2f(h2.w);
            a0 += v3 * b2f(h3.x); a1 += v3 * b2f(h3.y);
            a2 += v3 * b2f(h3.z); a3 += v3 * b2f(h3.w);
        }
        for (; j < nb; j++) {
            int   cj = __shfl(c, j);
            float vj = __shfl(v, j);
            ushort4 hh = *(const ushort4*)(sup + (size_t)cj * 256 + lane * 4);
            a0 += vj * b2f(hh.x); a1 += vj * b2f(hh.y);
            a2 += vj * b2f(hh.z); a3 += vj * b2f(hh.w);
        }
    }

    float4 o;
    o.x = a0 > 0.f ? a0 : 0.f;
    o.y = a1 > 0.f ? a1 : 0.f;
    o.z = a2 > 0.f ? a2 : 0.f;
    o.w = a3 > 0.f ? a3 : 0.f;
    *(float4*)(out + (size_t)row * 256 + lane * 4) = o;
}

// ---------------------------------------------------------------------------
extern "C" void kernel_launch(void* const* d_in, const int* in_sizes, int n_in,
                              void* d_out, int out_size, void* d_ws, size_t ws_size,
                              hipStream_t stream) {
    const float* features = (const float*)d_in[0];
    const float* weight   = (const float*)d_in[1];
    const int*   adj_row  = (const int*)d_in[2];
    const int*   adj_col  = (const int*)d_in[3];
    const float* adj_val  = (const float*)d_in[4];
    float* out = (float*)d_out;

    char* ws = (char*)d_ws;
    size_t off = 0;
    auto alloc = [&](size_t bytes) -> char* {
        char* p = ws + off;
        off = (off + bytes + 255) & ~(size_t)255;
        return p;
    };
    unsigned short* sup     = (unsigned short*)alloc((size_t)N_NODES * 256 * 2); // 51.2 MB
    unsigned short* BT      = (unsigned short*)alloc(256 * 256 * 2);
    int*            counts  = (int*)alloc((size_t)N_NODES * 4);
    int*            offsets = (int*)alloc((size_t)N_NODES * 4);
    int*            ghist   = (int*)alloc(512 * 4);
    int*            bbase   = (int*)alloc(512 * 4);
    int*            gcur    = (int*)alloc(512 * 4);
    int2*           bucket  = (int2*)alloc((size_t)N_EDGES * 8);                 // 25.6 MB
    unsigned int*   csr     = (unsigned int*)alloc((size_t)N_EDGES * 4);         // 12.8 MB

    hipMemsetAsync(ghist, 0, 512 * 4, stream);

    transpose_b<<<256, 256, 0, stream>>>(weight, BT);
    gemm_dma<<<782, 512, 0, stream>>>(features, BT, sup);          // ceil(100000/128)
    bhist_kernel<<<782, 256, 0, stream>>>(adj_row, ghist);         // ceil(3.2M/4096)
    bscan_kernel<<<1, 512, 0, stream>>>(ghist, bbase, gcur);
    bin2_kernel<<<782, 512, 0, stream>>>(adj_row, adj_col, adj_val, gcur, bucket);
    csort_kernel<<<NBUCK, 512, 0, stream>>>(bucket, bbase, gcur, csr, offsets, counts);
    spmm_kernel<<<25000, 256, 0, stream>>>(sup, offsets, counts, csr, out);
}

// Round 3
// 502.641 us; speedup vs baseline: 1.6228x; 1.0167x over previous
//
#include <hip/hip_runtime.h>
#include <hip/hip_bf16.h>

#define N_NODES 100000
#define N_EDGES 3200000
#define NBUCK   391          // ceil(100000 / 256) buckets of 256 rows

typedef short v8s __attribute__((ext_vector_type(8)));
typedef float v4f __attribute__((ext_vector_type(4)));
typedef unsigned short v8u __attribute__((ext_vector_type(8)));

__device__ __forceinline__ unsigned short f2b(float x) {
    __hip_bfloat16 h = __float2bfloat16(x);
    return *reinterpret_cast<unsigned short*>(&h);
}
__device__ __forceinline__ float b2f(unsigned short u) {
    return __uint_as_float(((unsigned int)u) << 16);
}

// async global->LDS, 16B per lane.
__device__ __forceinline__ void gld16(const void* g, void* l) {
    __builtin_amdgcn_global_load_lds(
        (const __attribute__((address_space(1))) void*)g,
        (__attribute__((address_space(3))) void*)l, 16, 0, 0);
}

// ---------------------------------------------------------------------------
// Pre-transpose + convert weight: B[k][n] fp32 -> BT[n][k] bf16
// ---------------------------------------------------------------------------
__global__ void transpose_b(const float* __restrict__ B, unsigned short* __restrict__ BT) {
    int n = blockIdx.x;
    int k = threadIdx.x;
    BT[n * 256 + k] = f2b(B[k * 256 + n]);
}

// ---------------------------------------------------------------------------
// GEMM (m97-style): 128x256 tile, 512 threads, BK=64, global_load_lds(16B).
// ---------------------------------------------------------------------------
__global__ __launch_bounds__(512)
void gemm_dma(const float* __restrict__ A, const unsigned short* __restrict__ BT,
              unsigned short* __restrict__ C) {
    __shared__ __align__(16) float          sA[128 * 64];   // 32 KB
    __shared__ __align__(16) unsigned short sB[256 * 64];   // 32 KB

    const int tid  = threadIdx.x;
    const int wave = tid >> 6;
    const int lane = tid & 63;
    const int quad = lane >> 4;
    const int l16  = lane & 15;
    const int row0 = blockIdx.x * 128;

    v4f acc[16];
#pragma unroll
    for (int t = 0; t < 16; t++) acc[t] = (v4f){0.f, 0.f, 0.f, 0.f};

    const int ml = wave * 16 + l16;

    for (int ks = 0; ks < 4; ks++) {
        const int kbase = ks * 64;
#pragma unroll
        for (int i = 0; i < 4; i++) {
            int s = i * 512 + tid;
            int m = s >> 4;
            int c = (s & 15) ^ (m & 15);
            int row = row0 + m;
            if (row >= N_NODES) row = row0;
            gld16(A + (size_t)row * 256 + kbase + c * 4, (char*)sA + (size_t)s * 16);
        }
#pragma unroll
        for (int i = 0; i < 4; i++) {
            int s = i * 512 + tid;
            int n = s >> 3;
            int c = (s & 7) ^ (n & 7);
            gld16(BT + (size_t)n * 256 + kbase + c * 8, (char*)sB + (size_t)s * 16);
        }
        __syncthreads();

#pragma unroll
        for (int sub = 0; sub < 2; sub++) {
            int ca  = sub * 8 + 2 * quad;
            int pa0 = ml * 16 + (ca ^ (ml & 15));
            int pa1 = ml * 16 + ((ca + 1) ^ (ml & 15));
            v4f lo = *(const v4f*)&sA[pa0 * 4];
            v4f hi = *(const v4f*)&sA[pa1 * 4];
            v8s af;
            af[0] = (short)f2b(lo[0]); af[1] = (short)f2b(lo[1]);
            af[2] = (short)f2b(lo[2]); af[3] = (short)f2b(lo[3]);
            af[4] = (short)f2b(hi[0]); af[5] = (short)f2b(hi[1]);
            af[6] = (short)f2b(hi[2]); af[7] = (short)f2b(hi[3]);
            int cb = sub * 4 + quad;
#pragma unroll
            for (int t = 0; t < 16; t++) {
                int n  = t * 16 + l16;
                int pb = n * 8 + (cb ^ (n & 7));
                v8s bf = *(const v8s*)&sB[pb * 8];
                acc[t] = __builtin_amdgcn_mfma_f32_16x16x32_bf16(af, bf, acc[t], 0, 0, 0);
            }
        }
        __syncthreads();
    }

    const int grow_base = row0 + wave * 16 + quad * 4;
#pragma unroll
    for (int t = 0; t < 16; t++) {
#pragma unroll
        for (int r = 0; r < 4; r++) {
            int grow = grow_base + r;
            if (grow < N_NODES)
                C[(size_t)grow * 256 + t * 16 + l16] = f2b(acc[t][r]);
        }
    }
}

// ---------------------------------------------------------------------------
// Coarse histogram over 391 buckets with LDS pre-aggregation.
// ---------------------------------------------------------------------------
__global__ __launch_bounds__(256)
void bhist_kernel(const int* __restrict__ row, int* __restrict__ ghist) {
    __shared__ int h[NBUCK];
    const int tid = threadIdx.x;
    for (int i = tid; i < NBUCK; i += 256) h[i] = 0;
    __syncthreads();
    const int e0 = blockIdx.x * 4096;
#pragma unroll
    for (int j = 0; j < 16; j++) {
        int e = e0 + j * 256 + tid;
        if (e < N_EDGES) atomicAdd(&h[row[e] >> 8], 1);
    }
    __syncthreads();
    for (int i = tid; i < NBUCK; i += 256)
        if (h[i]) atomicAdd(&ghist[i], h[i]);
}

// Exclusive scan of 391 bucket counts; also initializes the global cursors.
__global__ void bscan_kernel(const int* __restrict__ ghist, int* __restrict__ bbase,
                             int* __restrict__ gcur) {
    __shared__ int s[512];
    const int tid = threadIdx.x;   // 512 threads
    int x = (tid < NBUCK) ? ghist[tid] : 0;
    s[tid] = x;
    __syncthreads();
    for (int off = 1; off < 512; off <<= 1) {
        int v = (tid >= off) ? s[tid - off] : 0;
        __syncthreads();
        s[tid] += v;
        __syncthreads();
    }
    if (tid < NBUCK) {
        int b = s[tid] - x;
        bbase[tid] = b;
        gcur[tid]  = b;
    }
}

// ---------------------------------------------------------------------------
// Bin pass v3: LDS counting-sort of the block's 4096 edges by bucket, wave
// shuffle scan (2 barriers instead of 18), slim 6B entries (4B key + 2B val),
// 40KB LDS -> 4 blocks/CU. Copy-out: consecutive threads -> consecutive
// addresses within each bucket run.
// key = (row_local<<17) | col  (8+17 bits); val = bf15 (sign dropped, val>=0)
// ---------------------------------------------------------------------------
__global__ __launch_bounds__(512)
void bin3_kernel(const int* __restrict__ row, const int* __restrict__ col,
                 const float* __restrict__ val, int* __restrict__ gcur,
                 unsigned int* __restrict__ bucketK, unsigned short* __restrict__ bucketV) {
    __shared__ int cnt[512];
    __shared__ int ls[512];
    __shared__ int gb[512];
    __shared__ int lcur[512];
    __shared__ int wsum[8];
    __shared__ __align__(16) unsigned int   skey[4096];  // 16 KB
    __shared__ unsigned short sval[4096];                // 8 KB
    __shared__ unsigned short sbid[4096];                // 8 KB

    const int tid = threadIdx.x;
    const int e0  = blockIdx.x * 4096;

    int r[8], c[8];
    unsigned short v[8];
#pragma unroll
    for (int j = 0; j < 8; j++) {
        int e = e0 + j * 512 + tid;
        if (e < N_EDGES) {
            r[j] = row[e]; c[j] = col[e];
            v[j] = (unsigned short)((((unsigned int)__float_as_int(val[e]) + 0x8000u) >> 16) & 0x7FFFu);
        } else r[j] = -1;
    }

    cnt[tid] = 0;
    __syncthreads();
#pragma unroll
    for (int j = 0; j < 8; j++)
        if (r[j] >= 0) atomicAdd(&cnt[r[j] >> 8], 1);
    __syncthreads();

    int x = cnt[tid];
    // reserve this block's global range for bucket `tid` (aggregated atomic)
    gb[tid] = x ? atomicAdd(&gcur[tid], x) : 0;

    // wave-level exclusive scan over 512 slots (2 barriers total)
    const int lane = tid & 63, w = tid >> 6;
    int inc = x;
#pragma unroll
    for (int d = 1; d < 64; d <<= 1) {
        int t = __shfl_up(inc, d);
        if (lane >= d) inc += t;
    }
    if (lane == 63) wsum[w] = inc;
    __syncthreads();
    int pre = 0;
#pragma unroll
    for (int k = 0; k < 8; k++) pre += (k < w) ? wsum[k] : 0;
    int excl = pre + inc - x;
    ls[tid]   = excl;
    lcur[tid] = excl;
    __syncthreads();

    // place edges into LDS stage (sorted by bucket), remember bucket id
#pragma unroll
    for (int j = 0; j < 8; j++) {
        if (r[j] >= 0) {
            int b = r[j] >> 8;
            int q = atomicAdd(&lcur[b], 1);
            skey[q] = ((unsigned int)(r[j] & 255) << 17) | (unsigned int)c[j];
            sval[q] = v[j];
            sbid[q] = (unsigned short)b;
        }
    }
    __syncthreads();

    // copy-out: consecutive i -> consecutive addresses within runs
    int tot = N_EDGES - e0;
    if (tot > 4096) tot = 4096;
    for (int i = tid; i < tot; i += 512) {
        int b   = sbid[i];
        int dst = gb[b] + (i - ls[b]);
        bucketK[dst] = skey[i];
        bucketV[dst] = sval[i];
    }
}

// ---------------------------------------------------------------------------
// Per-bucket counting sort into final CSR (4B packed) + offs/counts.
// 1024 threads (~24 waves/CU at 391 blocks), wave shuffle scan.
// ---------------------------------------------------------------------------
__global__ __launch_bounds__(1024)
void csort3_kernel(const unsigned int* __restrict__ bucketK,
                   const unsigned short* __restrict__ bucketV,
                   const int* __restrict__ bbase, const int* __restrict__ gcur,
                   unsigned int* __restrict__ csr,
                   int* __restrict__ offs, int* __restrict__ counts) {
    __shared__ int h[256];
    __shared__ int cur[256];
    __shared__ int wsum4[4];
    const int tid  = threadIdx.x;         // 1024 threads
    const int b    = blockIdx.x;
    const int base = bbase[b];
    const int end  = gcur[b];             // after bin pass: base + bucket size

    if (tid < 256) h[tid] = 0;
    __syncthreads();
    for (int i = base + tid; i < end; i += 1024)
        atomicAdd(&h[bucketK[i] >> 17], 1);
    __syncthreads();

    int x = 0, inc = 0;
    if (tid < 256) {                       // waves 0-3, uniform branch
        x = h[tid];
        inc = x;
        const int lane = tid & 63;
#pragma unroll
        for (int d = 1; d < 64; d <<= 1) {
            int t = __shfl_up(inc, d);
            if (lane >= d) inc += t;
        }
        if (lane == 63) wsum4[tid >> 6] = inc;
    }
    __syncthreads();
    if (tid < 256) {
        int pre = 0;
#pragma unroll
        for (int k = 0; k < 4; k++) pre += (k < (tid >> 6)) ? wsum4[k] : 0;
        int excl = pre + inc - x;
        int grow = b * 256 + tid;
        if (grow < N_NODES) {
            offs[grow]   = base + excl;
            counts[grow] = x;
        }
        cur[tid] = base + excl;
    }
    __syncthreads();

    for (int i = base + tid; i < end; i += 1024) {
        unsigned int k   = bucketK[i];
        unsigned int v15 = bucketV[i];
        int rl = (int)(k >> 17);
        int p  = atomicAdd(&cur[rl], 1);
        csr[p] = (v15 << 17) | (k & 0x1FFFFu);
    }
}

// ---------------------------------------------------------------------------
// SpMM half-width: one wave per row, 128 output cols per pass.
// lane = q(2b) x c16(4b): lane covers 8 cols (16B ushort8 load), processes
// edges with index = 4*g + q. Cross-q reduce via shfl_xor at the end.
// Two sequential passes halve the instantaneous sup working set (L2 capacity).
// ---------------------------------------------------------------------------
__global__ __launch_bounds__(256)
void spmm_half(const unsigned short* __restrict__ sup,
               const int* __restrict__ offs, const int* __restrict__ counts,
               const unsigned int* __restrict__ csr, float* __restrict__ out,
               const int cbase) {
    const int wave = threadIdx.x >> 6;
    const int lane = threadIdx.x & 63;
    const int row  = blockIdx.x * 4 + wave;
    if (row >= N_NODES) return;

    const int q   = lane >> 4;
    const int c16 = lane & 15;
    const unsigned short* supc = sup + cbase + c16 * 8;

    const int start = offs[row];
    const int deg   = counts[row];

    float a[8];
#pragma unroll
    for (int k = 0; k < 8; k++) a[k] = 0.f;

    for (int base2 = 0; base2 < deg; base2 += 64) {
        int nb = deg - base2;
        if (nb > 64) nb = 64;
        int c = 0;
        float v = 0.f;
        if (lane < nb) {
            unsigned int w = csr[start + base2 + lane];
            c = (int)(w & 0x1FFFFu);
            v = __uint_as_float((w >> 17) << 16);
        }
        int ng = (nb + 3) >> 2;            // groups of 4 edges
        int g = 0;
        for (; g + 4 <= ng; g += 4) {
            int cc[4]; float vv[4];
#pragma unroll
            for (int u = 0; u < 4; u++) {
                int idx = (g + u) * 4 + q;      // per-lane edge index (<64)
                cc[u] = __shfl(c, idx);
                vv[u] = __shfl(v, idx);
            }
            v8u h[4];
#pragma unroll
            for (int u = 0; u < 4; u++)
                h[u] = *(const v8u*)(supc + (size_t)cc[u] * 256);
#pragma unroll
            for (int u = 0; u < 4; u++) {
#pragma unroll
                for (int k = 0; k < 8; k++)
                    a[k] += vv[u] * b2f(h[u][k]);
            }
        }
        for (; g < ng; g++) {
            int idx = g * 4 + q;
            int   cc = __shfl(c, idx);
            float vv = __shfl(v, idx);
            v8u h = *(const v8u*)(supc + (size_t)cc * 256);
#pragma unroll
            for (int k = 0; k < 8; k++)
                a[k] += vv * b2f(h[k]);
        }
    }

    // combine the 4 edge-residue partials (q = 0..3)
#pragma unroll
    for (int k = 0; k < 8; k++) {
        a[k] += __shfl_xor(a[k], 16);
        a[k] += __shfl_xor(a[k], 32);
    }

    if (lane < 32) {
        int q2 = lane >> 4;                // 0 or 1 -> which float4 of the block
        int cl = lane & 15;
        float4 o;
        o.x = a[q2 * 4 + 0] > 0.f ? a[q2 * 4 + 0] : 0.f;
        o.y = a[q2 * 4 + 1] > 0.f ? a[q2 * 4 + 1] : 0.f;
        o.z = a[q2 * 4 + 2] > 0.f ? a[q2 * 4 + 2] : 0.f;
        o.w = a[q2 * 4 + 3] > 0.f ? a[q2 * 4 + 3] : 0.f;
        *(float4*)(out + (size_t)row * 256 + cbase + cl * 8 + q2 * 4) = o;
    }
}

// ---------------------------------------------------------------------------
extern "C" void kernel_launch(void* const* d_in, const int* in_sizes, int n_in,
                              void* d_out, int out_size, void* d_ws, size_t ws_size,
                              hipStream_t stream) {
    const float* features = (const float*)d_in[0];
    const float* weight   = (const float*)d_in[1];
    const int*   adj_row  = (const int*)d_in[2];
    const int*   adj_col  = (const int*)d_in[3];
    const float* adj_val  = (const float*)d_in[4];
    float* out = (float*)d_out;

    char* ws = (char*)d_ws;
    size_t off = 0;
    auto alloc = [&](size_t bytes) -> char* {
        char* p = ws + off;
        off = (off + bytes + 255) & ~(size_t)255;
        return p;
    };
    unsigned short* sup     = (unsigned short*)alloc((size_t)N_NODES * 256 * 2); // 51.2 MB
    unsigned short* BT      = (unsigned short*)alloc(256 * 256 * 2);
    int*            counts  = (int*)alloc((size_t)N_NODES * 4);
    int*            offsets = (int*)alloc((size_t)N_NODES * 4);
    int*            ghist   = (int*)alloc(512 * 4);
    int*            bbase   = (int*)alloc(512 * 4);
    int*            gcur    = (int*)alloc(512 * 4);
    unsigned int*   bucketK = (unsigned int*)alloc((size_t)N_EDGES * 4);         // 12.8 MB
    unsigned short* bucketV = (unsigned short*)alloc((size_t)N_EDGES * 2);       //  6.4 MB
    unsigned int*   csr     = (unsigned int*)alloc((size_t)N_EDGES * 4);         // 12.8 MB

    hipMemsetAsync(ghist, 0, 512 * 4, stream);

    transpose_b<<<256, 256, 0, stream>>>(weight, BT);
    gemm_dma<<<782, 512, 0, stream>>>(features, BT, sup);          // ceil(100000/128)
    bhist_kernel<<<782, 256, 0, stream>>>(adj_row, ghist);         // ceil(3.2M/4096)
    bscan_kernel<<<1, 512, 0, stream>>>(ghist, bbase, gcur);
    bin3_kernel<<<782, 512, 0, stream>>>(adj_row, adj_col, adj_val, gcur, bucketK, bucketV);
    csort3_kernel<<<NBUCK, 1024, 0, stream>>>(bucketK, bucketV, bbase, gcur, csr, offsets, counts);
    spmm_half<<<25000, 256, 0, stream>>>(sup, offsets, counts, csr, out, 0);
    spmm_half<<<25000, 256, 0, stream>>>(sup, offsets, counts, csr, out, 128);
}

// Round 4
// 477.347 us; speedup vs baseline: 1.7088x; 1.0530x over previous
//
#include <hip/hip_runtime.h>
#include <hip/hip_bf16.h>

#define N_NODES 100000
#define N_EDGES 3200000
#define NBUCK   391          // ceil(100000 / 256) buckets of 256 rows
#define NBLKE   782          // ceil(3.2M / 4096) edge blocks
#define CAP_R   9600         // padded per-bucket csr region (mean 8184, sigma~90)

typedef short v8s __attribute__((ext_vector_type(8)));
typedef float v4f __attribute__((ext_vector_type(4)));
typedef unsigned short v8u __attribute__((ext_vector_type(8)));

__device__ __forceinline__ unsigned short f2b(float x) {
    __hip_bfloat16 h = __float2bfloat16(x);
    return *reinterpret_cast<unsigned short*>(&h);
}
__device__ __forceinline__ float b2f(unsigned short u) {
    return __uint_as_float(((unsigned int)u) << 16);
}

// async global->LDS, 16B per lane.
__device__ __forceinline__ void gld16(const void* g, void* l) {
    __builtin_amdgcn_global_load_lds(
        (const __attribute__((address_space(1))) void*)g,
        (__attribute__((address_space(3))) void*)l, 16, 0, 0);
}

// ---------------------------------------------------------------------------
// Pre-transpose + convert weight: B[k][n] fp32 -> BT[n][k] bf16
// ---------------------------------------------------------------------------
__global__ void transpose_b(const float* __restrict__ B, unsigned short* __restrict__ BT) {
    int n = blockIdx.x;
    int k = threadIdx.x;
    BT[n * 256 + k] = f2b(B[k * 256 + n]);
}

// ---------------------------------------------------------------------------
// GEMM (m97-style): 128x256 tile, 512 threads, BK=64, global_load_lds(16B).
// ---------------------------------------------------------------------------
__global__ __launch_bounds__(512)
void gemm_dma(const float* __restrict__ A, const unsigned short* __restrict__ BT,
              unsigned short* __restrict__ C) {
    __shared__ __align__(16) float          sA[128 * 64];   // 32 KB
    __shared__ __align__(16) unsigned short sB[256 * 64];   // 32 KB

    const int tid  = threadIdx.x;
    const int wave = tid >> 6;
    const int lane = tid & 63;
    const int quad = lane >> 4;
    const int l16  = lane & 15;
    const int row0 = blockIdx.x * 128;

    v4f acc[16];
#pragma unroll
    for (int t = 0; t < 16; t++) acc[t] = (v4f){0.f, 0.f, 0.f, 0.f};

    const int ml = wave * 16 + l16;

    for (int ks = 0; ks < 4; ks++) {
        const int kbase = ks * 64;
#pragma unroll
        for (int i = 0; i < 4; i++) {
            int s = i * 512 + tid;
            int m = s >> 4;
            int c = (s & 15) ^ (m & 15);
            int row = row0 + m;
            if (row >= N_NODES) row = row0;
            gld16(A + (size_t)row * 256 + kbase + c * 4, (char*)sA + (size_t)s * 16);
        }
#pragma unroll
        for (int i = 0; i < 4; i++) {
            int s = i * 512 + tid;
            int n = s >> 3;
            int c = (s & 7) ^ (n & 7);
            gld16(BT + (size_t)n * 256 + kbase + c * 8, (char*)sB + (size_t)s * 16);
        }
        __syncthreads();

#pragma unroll
        for (int sub = 0; sub < 2; sub++) {
            int ca  = sub * 8 + 2 * quad;
            int pa0 = ml * 16 + (ca ^ (ml & 15));
            int pa1 = ml * 16 + ((ca + 1) ^ (ml & 15));
            v4f lo = *(const v4f*)&sA[pa0 * 4];
            v4f hi = *(const v4f*)&sA[pa1 * 4];
            v8s af;
            af[0] = (short)f2b(lo[0]); af[1] = (short)f2b(lo[1]);
            af[2] = (short)f2b(lo[2]); af[3] = (short)f2b(lo[3]);
            af[4] = (short)f2b(hi[0]); af[5] = (short)f2b(hi[1]);
            af[6] = (short)f2b(hi[2]); af[7] = (short)f2b(hi[3]);
            int cb = sub * 4 + quad;
#pragma unroll
            for (int t = 0; t < 16; t++) {
                int n  = t * 16 + l16;
                int pb = n * 8 + (cb ^ (n & 7));
                v8s bf = *(const v8s*)&sB[pb * 8];
                acc[t] = __builtin_amdgcn_mfma_f32_16x16x32_bf16(af, bf, acc[t], 0, 0, 0);
            }
        }
        __syncthreads();
    }

    const int grow_base = row0 + wave * 16 + quad * 4;
#pragma unroll
    for (int t = 0; t < 16; t++) {
#pragma unroll
        for (int r = 0; r < 4; r++) {
            int grow = grow_base + r;
            if (grow < N_NODES)
                C[(size_t)grow * 256 + t * 16 + l16] = f2b(acc[t][r]);
        }
    }
}

// ---------------------------------------------------------------------------
// Bin pass v4: ZERO global atomics, no histogram/scan kernels needed.
// Each block owns edges [blockIdx*4096, +4096): bucket-sort them in LDS,
// write the permuted slice COALESCED at blockIdx*4096, plus a packed run
// descriptor runs[b][blk] = (local_start<<13 | count) for csort to gather.
// key = (row_local<<17) | col; val = bf15 (sign dropped, vals >= 0).
// ---------------------------------------------------------------------------
__global__ __launch_bounds__(512)
void bin4_kernel(const int* __restrict__ row, const int* __restrict__ col,
                 const float* __restrict__ val,
                 unsigned int* __restrict__ bucketK, unsigned short* __restrict__ bucketV,
                 unsigned int* __restrict__ runs) {
    __shared__ int cnt[512];
    __shared__ int lcur[512];
    __shared__ int wsum[8];
    __shared__ __align__(16) unsigned int   skey[4096];  // 16 KB
    __shared__ unsigned short sval[4096];                // 8 KB

    const int tid = threadIdx.x;
    const int e0  = blockIdx.x * 4096;

    int r[8], c[8];
    unsigned short v[8];
#pragma unroll
    for (int j = 0; j < 8; j++) {
        int e = e0 + j * 512 + tid;
        if (e < N_EDGES) {
            r[j] = row[e]; c[j] = col[e];
            v[j] = (unsigned short)((((unsigned int)__float_as_int(val[e]) + 0x8000u) >> 16) & 0x7FFFu);
        } else r[j] = -1;
    }

    cnt[tid] = 0;
    __syncthreads();
#pragma unroll
    for (int j = 0; j < 8; j++)
        if (r[j] >= 0) atomicAdd(&cnt[r[j] >> 8], 1);
    __syncthreads();

    const int lane = tid & 63, w = tid >> 6;
    int x = cnt[tid];
    int inc = x;
#pragma unroll
    for (int d = 1; d < 64; d <<= 1) {
        int t = __shfl_up(inc, d);
        if (lane >= d) inc += t;
    }
    if (lane == 63) wsum[w] = inc;
    __syncthreads();
    int pre = 0;
#pragma unroll
    for (int k = 0; k < 8; k++) pre += (k < w) ? wsum[k] : 0;
    int excl = pre + inc - x;
    lcur[tid] = excl;
    // run descriptor: local start (13b) | count (13b)
    if (tid < NBUCK)
        runs[(size_t)tid * NBLKE + blockIdx.x] =
            ((unsigned int)excl << 13) | (unsigned int)x;
    __syncthreads();

    // place edges into LDS stage (bucket-sorted)
#pragma unroll
    for (int j = 0; j < 8; j++) {
        if (r[j] >= 0) {
            int b = r[j] >> 8;
            int q = atomicAdd(&lcur[b], 1);
            skey[q] = ((unsigned int)(r[j] & 255) << 17) | (unsigned int)c[j];
            sval[q] = v[j];
        }
    }
    __syncthreads();

    // copy-out: fully coalesced, full-line writes at this block's own region
    int tot = N_EDGES - e0;
    if (tot > 4096) tot = 4096;
    for (int i = tid; i < tot; i += 512) {
        bucketK[e0 + i] = skey[i];
        bucketV[e0 + i] = sval[i];
    }
}

// ---------------------------------------------------------------------------
// csort v4: per bucket, gather the 782 runs into LDS (one wave per run),
// counting-sort by row in LDS, write csr into the bucket's PADDED region
// [b*CAP_R, ...). spmm uses absolute offs/counts so csr holes are free.
// ---------------------------------------------------------------------------
__global__ __launch_bounds__(1024)
void csort4_kernel(const unsigned int* __restrict__ bucketK,
                   const unsigned short* __restrict__ bucketV,
                   const unsigned int* __restrict__ runs,
                   unsigned int* __restrict__ csr,
                   int* __restrict__ offs, int* __restrict__ counts) {
    __shared__ unsigned int   skey[CAP_R];     // 37.5 KB
    __shared__ unsigned short sval[CAP_R];     // 18.75 KB
    __shared__ int rstart[NBLKE];
    __shared__ int rofs[NBLKE];
    __shared__ int rcnt[NBLKE];
    __shared__ int h[256];
    __shared__ int cur[256];
    __shared__ int wsum4[4];
    __shared__ int stot;

    const int tid  = threadIdx.x;              // 1024 threads, 16 waves
    const int b    = blockIdx.x;
    const int base = b * CAP_R;
    const int w    = tid >> 6, lane = tid & 63;

    if (tid == 0) stot = 0;
    if (tid < 256) h[tid] = 0;
    __syncthreads();

    // phase A: read this bucket's 782 descriptors (coalesced), reserve LDS ranges
    if (tid < NBLKE) {
        unsigned int d = runs[(size_t)b * NBLKE + tid];
        int c = (int)(d & 0x1FFFu);
        rstart[tid] = tid * 4096 + (int)(d >> 13);
        rcnt[tid]   = c;
        rofs[tid]   = c ? atomicAdd(&stot, c) : 0;
    }
    __syncthreads();

    // phase B: gather runs into LDS, one wave per run
    for (int rr = w; rr < NBLKE; rr += 16) {
        int c   = rcnt[rr];
        int src = rstart[rr];
        int dst = rofs[rr];
        for (int i = lane; i < c; i += 64) {
            skey[dst + i] = bucketK[src + i];
            sval[dst + i] = bucketV[src + i];
        }
    }
    __syncthreads();

    // phase C: counting sort by row_local within LDS
    const int n = stot;
    for (int i = tid; i < n; i += 1024)
        atomicAdd(&h[skey[i] >> 17], 1);
    __syncthreads();

    int x = 0, inc = 0;
    if (tid < 256) {
        x = h[tid];
        inc = x;
#pragma unroll
        for (int d = 1; d < 64; d <<= 1) {
            int t = __shfl_up(inc, d);
            if (lane >= d) inc += t;
        }
        if (lane == 63) wsum4[w] = inc;
    }
    __syncthreads();
    if (tid < 256) {
        int pre = 0;
#pragma unroll
        for (int k = 0; k < 4; k++) pre += (k < w) ? wsum4[k] : 0;
        int excl = pre + inc - x;
        int grow = b * 256 + tid;
        if (grow < N_NODES) {
            offs[grow]   = base + excl;
            counts[grow] = x;
        }
        cur[tid] = base + excl;
    }
    __syncthreads();

    for (int i = tid; i < n; i += 1024) {
        unsigned int k = skey[i];
        int rl = (int)(k >> 17);
        int p  = atomicAdd(&cur[rl], 1);
        csr[p] = ((unsigned int)sval[i] << 17) | (k & 0x1FFFFu);
    }
}

// ---------------------------------------------------------------------------
// SpMM half-width: one wave per row, 128 output cols per pass (unchanged).
// ---------------------------------------------------------------------------
__global__ __launch_bounds__(256)
void spmm_half(const unsigned short* __restrict__ sup,
               const int* __restrict__ offs, const int* __restrict__ counts,
               const unsigned int* __restrict__ csr, float* __restrict__ out,
               const int cbase) {
    const int wave = threadIdx.x >> 6;
    const int lane = threadIdx.x & 63;
    const int row  = blockIdx.x * 4 + wave;
    if (row >= N_NODES) return;

    const int q   = lane >> 4;
    const int c16 = lane & 15;
    const unsigned short* supc = sup + cbase + c16 * 8;

    const int start = offs[row];
    const int deg   = counts[row];

    float a[8];
#pragma unroll
    for (int k = 0; k < 8; k++) a[k] = 0.f;

    for (int base2 = 0; base2 < deg; base2 += 64) {
        int nb = deg - base2;
        if (nb > 64) nb = 64;
        int c = 0;
        float v = 0.f;
        if (lane < nb) {
            unsigned int w = csr[start + base2 + lane];
            c = (int)(w & 0x1FFFFu);
            v = __uint_as_float((w >> 17) << 16);
        }
        int ng = (nb + 3) >> 2;            // groups of 4 edges
        int g = 0;
        for (; g + 4 <= ng; g += 4) {
            int cc[4]; float vv[4];
#pragma unroll
            for (int u = 0; u < 4; u++) {
                int idx = (g + u) * 4 + q;
                cc[u] = __shfl(c, idx);
                vv[u] = __shfl(v, idx);
            }
            v8u h[4];
#pragma unroll
            for (int u = 0; u < 4; u++)
                h[u] = *(const v8u*)(supc + (size_t)cc[u] * 256);
#pragma unroll
            for (int u = 0; u < 4; u++) {
#pragma unroll
                for (int k = 0; k < 8; k++)
                    a[k] += vv[u] * b2f(h[u][k]);
            }
        }
        for (; g < ng; g++) {
            int idx = g * 4 + q;
            int   cc = __shfl(c, idx);
            float vv = __shfl(v, idx);
            v8u h = *(const v8u*)(supc + (size_t)cc * 256);
#pragma unroll
            for (int k = 0; k < 8; k++)
                a[k] += vv * b2f(h[k]);
        }
    }

#pragma unroll
    for (int k = 0; k < 8; k++) {
        a[k] += __shfl_xor(a[k], 16);
        a[k] += __shfl_xor(a[k], 32);
    }

    if (lane < 32) {
        int q2 = lane >> 4;
        int cl = lane & 15;
        float4 o;
        o.x = a[q2 * 4 + 0] > 0.f ? a[q2 * 4 + 0] : 0.f;
        o.y = a[q2 * 4 + 1] > 0.f ? a[q2 * 4 + 1] : 0.f;
        o.z = a[q2 * 4 + 2] > 0.f ? a[q2 * 4 + 2] : 0.f;
        o.w = a[q2 * 4 + 3] > 0.f ? a[q2 * 4 + 3] : 0.f;
        *(float4*)(out + (size_t)row * 256 + cbase + cl * 8 + q2 * 4) = o;
    }
}

// ---------------------------------------------------------------------------
extern "C" void kernel_launch(void* const* d_in, const int* in_sizes, int n_in,
                              void* d_out, int out_size, void* d_ws, size_t ws_size,
                              hipStream_t stream) {
    const float* features = (const float*)d_in[0];
    const float* weight   = (const float*)d_in[1];
    const int*   adj_row  = (const int*)d_in[2];
    const int*   adj_col  = (const int*)d_in[3];
    const float* adj_val  = (const float*)d_in[4];
    float* out = (float*)d_out;

    char* ws = (char*)d_ws;
    size_t off = 0;
    auto alloc = [&](size_t bytes) -> char* {
        char* p = ws + off;
        off = (off + bytes + 255) & ~(size_t)255;
        return p;
    };
    unsigned short* sup     = (unsigned short*)alloc((size_t)N_NODES * 256 * 2);   // 51.2 MB
    unsigned short* BT      = (unsigned short*)alloc(256 * 256 * 2);
    int*            counts  = (int*)alloc((size_t)N_NODES * 4);
    int*            offsets = (int*)alloc((size_t)N_NODES * 4);
    unsigned int*   bucketK = (unsigned int*)alloc((size_t)N_EDGES * 4);           // 12.8 MB
    unsigned short* bucketV = (unsigned short*)alloc((size_t)N_EDGES * 2);         //  6.4 MB
    unsigned int*   runs    = (unsigned int*)alloc((size_t)NBUCK * NBLKE * 4);     //  1.2 MB
    unsigned int*   csr     = (unsigned int*)alloc((size_t)NBUCK * CAP_R * 4);     // 15.0 MB

    transpose_b<<<256, 256, 0, stream>>>(weight, BT);
    gemm_dma<<<782, 512, 0, stream>>>(features, BT, sup);          // ceil(100000/128)
    bin4_kernel<<<NBLKE, 512, 0, stream>>>(adj_row, adj_col, adj_val, bucketK, bucketV, runs);
    csort4_kernel<<<NBUCK, 1024, 0, stream>>>(bucketK, bucketV, runs, csr, offsets, counts);
    spmm_half<<<25000, 256, 0, stream>>>(sup, offsets, counts, csr, out, 0);
    spmm_half<<<25000, 256, 0, stream>>>(sup, offsets, counts, csr, out, 128);
}

// Round 5
// 443.259 us; speedup vs baseline: 1.8402x; 1.0769x over previous
//
#include <hip/hip_runtime.h>
#include <hip/hip_bf16.h>

#define N_NODES 100000
#define N_EDGES 3200000
#define NBUCK   391          // ceil(100000 / 256) buckets of 256 rows
#define NBLKE   782          // ceil(3.2M / 4096) edge blocks
#define CAP_R   9600         // padded per-bucket csr region (mean 8184, ~15 sigma)

typedef short v8s __attribute__((ext_vector_type(8)));
typedef float v4f __attribute__((ext_vector_type(4)));
typedef unsigned short v8u __attribute__((ext_vector_type(8)));

__device__ __forceinline__ unsigned short f2b(float x) {
    __hip_bfloat16 h = __float2bfloat16(x);
    return *reinterpret_cast<unsigned short*>(&h);
}
__device__ __forceinline__ float b2f(unsigned short u) {
    return __uint_as_float(((unsigned int)u) << 16);
}

// async global->LDS, 16B per lane.
__device__ __forceinline__ void gld16(const void* g, void* l) {
    __builtin_amdgcn_global_load_lds(
        (const __attribute__((address_space(1))) void*)g,
        (__attribute__((address_space(3))) void*)l, 16, 0, 0);
}

// ---------------------------------------------------------------------------
// Pre-transpose + convert weight: B[k][n] fp32 -> BT[n][k] bf16
// ---------------------------------------------------------------------------
__global__ void transpose_b(const float* __restrict__ B, unsigned short* __restrict__ BT) {
    int n = blockIdx.x;
    int k = threadIdx.x;
    BT[n * 256 + k] = f2b(B[k * 256 + n]);
}

// ---------------------------------------------------------------------------
// GEMM (m97-style): 128x256 tile, 512 threads, BK=64, global_load_lds(16B).
// ---------------------------------------------------------------------------
__global__ __launch_bounds__(512)
void gemm_dma(const float* __restrict__ A, const unsigned short* __restrict__ BT,
              unsigned short* __restrict__ C) {
    __shared__ __align__(16) float          sA[128 * 64];   // 32 KB
    __shared__ __align__(16) unsigned short sB[256 * 64];   // 32 KB

    const int tid  = threadIdx.x;
    const int wave = tid >> 6;
    const int lane = tid & 63;
    const int quad = lane >> 4;
    const int l16  = lane & 15;
    const int row0 = blockIdx.x * 128;

    v4f acc[16];
#pragma unroll
    for (int t = 0; t < 16; t++) acc[t] = (v4f){0.f, 0.f, 0.f, 0.f};

    const int ml = wave * 16 + l16;

    for (int ks = 0; ks < 4; ks++) {
        const int kbase = ks * 64;
#pragma unroll
        for (int i = 0; i < 4; i++) {
            int s = i * 512 + tid;
            int m = s >> 4;
            int c = (s & 15) ^ (m & 15);
            int row = row0 + m;
            if (row >= N_NODES) row = row0;
            gld16(A + (size_t)row * 256 + kbase + c * 4, (char*)sA + (size_t)s * 16);
        }
#pragma unroll
        for (int i = 0; i < 4; i++) {
            int s = i * 512 + tid;
            int n = s >> 3;
            int c = (s & 7) ^ (n & 7);
            gld16(BT + (size_t)n * 256 + kbase + c * 8, (char*)sB + (size_t)s * 16);
        }
        __syncthreads();

#pragma unroll
        for (int sub = 0; sub < 2; sub++) {
            int ca  = sub * 8 + 2 * quad;
            int pa0 = ml * 16 + (ca ^ (ml & 15));
            int pa1 = ml * 16 + ((ca + 1) ^ (ml & 15));
            v4f lo = *(const v4f*)&sA[pa0 * 4];
            v4f hi = *(const v4f*)&sA[pa1 * 4];
            v8s af;
            af[0] = (short)f2b(lo[0]); af[1] = (short)f2b(lo[1]);
            af[2] = (short)f2b(lo[2]); af[3] = (short)f2b(lo[3]);
            af[4] = (short)f2b(hi[0]); af[5] = (short)f2b(hi[1]);
            af[6] = (short)f2b(hi[2]); af[7] = (short)f2b(hi[3]);
            int cb = sub * 4 + quad;
#pragma unroll
            for (int t = 0; t < 16; t++) {
                int n  = t * 16 + l16;
                int pb = n * 8 + (cb ^ (n & 7));
                v8s bf = *(const v8s*)&sB[pb * 8];
                acc[t] = __builtin_amdgcn_mfma_f32_16x16x32_bf16(af, bf, acc[t], 0, 0, 0);
            }
        }
        __syncthreads();
    }

    const int grow_base = row0 + wave * 16 + quad * 4;
#pragma unroll
    for (int t = 0; t < 16; t++) {
#pragma unroll
        for (int r = 0; r < 4; r++) {
            int grow = grow_base + r;
            if (grow < N_NODES)
                C[(size_t)grow * 256 + t * 16 + l16] = f2b(acc[t][r]);
        }
    }
}

// ---------------------------------------------------------------------------
// Bin pass v5: single LDS-atomic pass records per-edge rank in REGISTERS;
// placement is then plain ds_writes (half the LDS atomics of v4).
// Block owns edges [blockIdx*4096, +4096): bucket-sort in LDS, write the
// permuted slice coalesced at blockIdx*4096, plus run descriptors
// runs[b][blk] = (local_start<<13 | count).
// key = (row_local<<17) | col; val = bf15 (sign dropped, vals >= 0).
// ---------------------------------------------------------------------------
__global__ __launch_bounds__(512)
void bin5_kernel(const int* __restrict__ row, const int* __restrict__ col,
                 const float* __restrict__ val,
                 unsigned int* __restrict__ bucketK, unsigned short* __restrict__ bucketV,
                 unsigned int* __restrict__ runs) {
    __shared__ int cnt[512];
    __shared__ int ls[512];
    __shared__ int wsum[8];
    __shared__ __align__(16) unsigned int   skey[4096];  // 16 KB
    __shared__ unsigned short sval[4096];                // 8 KB

    const int tid = threadIdx.x;
    const int e0  = blockIdx.x * 4096;

    int r[8], c[8], rank[8];
    unsigned short v[8];
#pragma unroll
    for (int j = 0; j < 8; j++) {
        int e = e0 + j * 512 + tid;
        if (e < N_EDGES) {
            r[j] = row[e]; c[j] = col[e];
            v[j] = (unsigned short)((((unsigned int)__float_as_int(val[e]) + 0x8000u) >> 16) & 0x7FFFu);
        } else r[j] = -1;
    }

    cnt[tid] = 0;
    __syncthreads();
#pragma unroll
    for (int j = 0; j < 8; j++)
        if (r[j] >= 0) rank[j] = atomicAdd(&cnt[r[j] >> 8], 1);
    __syncthreads();

    const int lane = tid & 63, w = tid >> 6;
    int x = cnt[tid];
    int inc = x;
#pragma unroll
    for (int d = 1; d < 64; d <<= 1) {
        int t = __shfl_up(inc, d);
        if (lane >= d) inc += t;
    }
    if (lane == 63) wsum[w] = inc;
    __syncthreads();
    int pre = 0;
#pragma unroll
    for (int k = 0; k < 8; k++) pre += (k < w) ? wsum[k] : 0;
    int excl = pre + inc - x;
    ls[tid] = excl;
    // run descriptor: local start (13b) | count (13b)
    if (tid < NBUCK)
        runs[(size_t)tid * NBLKE + blockIdx.x] =
            ((unsigned int)excl << 13) | (unsigned int)x;
    __syncthreads();

    // place edges into LDS stage (bucket-sorted) — NO atomics
#pragma unroll
    for (int j = 0; j < 8; j++) {
        if (r[j] >= 0) {
            int b = r[j] >> 8;
            int q = ls[b] + rank[j];
            skey[q] = ((unsigned int)(r[j] & 255) << 17) | (unsigned int)c[j];
            sval[q] = v[j];
        }
    }
    __syncthreads();

    // copy-out: fully coalesced, full-line writes at this block's own region
    int tot = N_EDGES - e0;
    if (tot > 4096) tot = 4096;
    for (int i = tid; i < tot; i += 512) {
        bucketK[e0 + i] = skey[i];
        bucketV[e0 + i] = sval[i];
    }
}

// ---------------------------------------------------------------------------
// csort v5: per bucket, deterministic scan of run counts, gather via binary
// search (ALL 1024 lanes active, coalesced within runs), counting-sort by
// row with register ranks (single LDS-atomic pass), scatter with plain
// stores into the bucket's padded csr region [b*CAP_R, ...).
// ---------------------------------------------------------------------------
__global__ __launch_bounds__(1024)
void csort5_kernel(const unsigned int* __restrict__ bucketK,
                   const unsigned short* __restrict__ bucketV,
                   const unsigned int* __restrict__ runs,
                   unsigned int* __restrict__ csr,
                   int* __restrict__ offs, int* __restrict__ counts) {
    __shared__ unsigned int   skey[CAP_R];     // 37.5 KB
    __shared__ unsigned short sval[CAP_R];     // 18.75 KB
    __shared__ int rstart[NBLKE];
    __shared__ int rofs[NBLKE + 1];
    __shared__ int h[256];
    __shared__ int sbase[256];
    __shared__ int wsum[16];
    __shared__ int wsum4[4];

    const int tid  = threadIdx.x;              // 1024 threads, 16 waves
    const int b    = blockIdx.x;
    const int base = b * CAP_R;
    const int w    = tid >> 6, lane = tid & 63;

    if (tid < 256) h[tid] = 0;

    // phase A: read descriptors + deterministic exclusive scan of counts
    int x = 0;
    if (tid < NBLKE) {
        unsigned int d = runs[(size_t)b * NBLKE + tid];
        x = (int)(d & 0x1FFFu);
        rstart[tid] = tid * 4096 + (int)(d >> 13);
    }
    int inc = x;
#pragma unroll
    for (int d = 1; d < 64; d <<= 1) {
        int t = __shfl_up(inc, d);
        if (lane >= d) inc += t;
    }
    if (lane == 63) wsum[w] = inc;
    __syncthreads();
    int pre = 0;
#pragma unroll
    for (int k = 0; k < 16; k++) pre += (k < w) ? wsum[k] : 0;
    int excl = pre + inc - x;
    if (tid <= NBLKE) rofs[tid] = excl;        // rofs[NBLKE] = total
    __syncthreads();

    const int n = rofs[NBLKE];

    // phase B: gather into LDS via binary search over run offsets
    for (int i = tid; i < n; i += 1024) {
        int lo = 0, hi = NBLKE - 1;
        while (lo < hi) {
            int mid = (lo + hi + 1) >> 1;
            if (rofs[mid] <= i) lo = mid; else hi = mid - 1;
        }
        int src = rstart[lo] + (i - rofs[lo]);
        skey[i] = bucketK[src];
        sval[i] = bucketV[src];
    }
    __syncthreads();

    // phase C: row histogram with REGISTER ranks (n <= CAP_R <= 10*1024)
    int rk[10];
#pragma unroll
    for (int k = 0; k < 10; k++) {
        int i = tid + k * 1024;
        if (i < n) rk[k] = atomicAdd(&h[skey[i] >> 17], 1);
    }
    __syncthreads();

    // phase D: exclusive scan of h (256) -> per-row bases
    int xx = 0, inc2 = 0;
    if (tid < 256) {
        xx = h[tid];
        inc2 = xx;
#pragma unroll
        for (int d = 1; d < 64; d <<= 1) {
            int t = __shfl_up(inc2, d);
            if (lane >= d) inc2 += t;
        }
        if (lane == 63) wsum4[w] = inc2;
    }
    __syncthreads();
    if (tid < 256) {
        int pre4 = 0;
#pragma unroll
        for (int k = 0; k < 4; k++) pre4 += (k < w) ? wsum4[k] : 0;
        int e2 = pre4 + inc2 - xx;
        int grow = b * 256 + tid;
        if (grow < N_NODES) {
            offs[grow]   = base + e2;
            counts[grow] = xx;
        }
        sbase[tid] = base + e2;
    }
    __syncthreads();

    // phase E: scatter with plain stores (rank already known)
#pragma unroll
    for (int k = 0; k < 10; k++) {
        int i = tid + k * 1024;
        if (i < n) {
            unsigned int kk = skey[i];
            int rl = (int)(kk >> 17);
            csr[sbase[rl] + rk[k]] = ((unsigned int)sval[i] << 17) | (kk & 0x1FFFFu);
        }
    }
}

// ---------------------------------------------------------------------------
// SpMM v4: 4 column-slices of 64 cols, slice = blockIdx&3. Under round-robin
// block->XCD dispatch, XCD x serves only slice (x&3): per-XCD sup working
// set 12.8 MB (vs 25.6), one 128B line per edge-access. One wave per row;
// lane = edge-slot q(3b) x col-chunk c8(3b); packed csr word shuffled once.
// ---------------------------------------------------------------------------
__global__ __launch_bounds__(256)
void spmm_s4(const unsigned short* __restrict__ sup,
             const int* __restrict__ offs, const int* __restrict__ counts,
             const unsigned int* __restrict__ csr, float* __restrict__ out) {
    const int slice  = blockIdx.x & 3;
    const int rowblk = blockIdx.x >> 2;
    const int wave = threadIdx.x >> 6;
    const int lane = threadIdx.x & 63;
    const int row  = rowblk * 4 + wave;
    if (row >= N_NODES) return;

    const int q  = lane >> 3;        // edge slot 0..7
    const int c8 = lane & 7;         // col chunk (8 cols)
    const unsigned short* supc = sup + slice * 64 + c8 * 8;

    const int start = offs[row];
    const int deg   = counts[row];

    float a[8];
#pragma unroll
    for (int k = 0; k < 8; k++) a[k] = 0.f;

    for (int base2 = 0; base2 < deg; base2 += 64) {
        int nb = deg - base2;
        if (nb > 64) nb = 64;
        unsigned int wd = 0;
        if (lane < nb) wd = csr[start + base2 + lane];
        int ng = (nb + 7) >> 3;
        int g = 0;
        for (; g + 2 <= ng; g += 2) {
            unsigned int w0 = __shfl(wd, g * 8 + q);
            unsigned int w1 = __shfl(wd, g * 8 + 8 + q);
            float v0 = __uint_as_float((w0 >> 17) << 16);
            float v1 = __uint_as_float((w1 >> 17) << 16);
            v8u h0 = *(const v8u*)(supc + (size_t)(w0 & 0x1FFFFu) * 256);
            v8u h1 = *(const v8u*)(supc + (size_t)(w1 & 0x1FFFFu) * 256);
#pragma unroll
            for (int k = 0; k < 8; k++) a[k] += v0 * b2f(h0[k]);
#pragma unroll
            for (int k = 0; k < 8; k++) a[k] += v1 * b2f(h1[k]);
        }
        for (; g < ng; g++) {
            unsigned int w0 = __shfl(wd, g * 8 + q);
            float v0 = __uint_as_float((w0 >> 17) << 16);
            v8u h0 = *(const v8u*)(supc + (size_t)(w0 & 0x1FFFFu) * 256);
#pragma unroll
            for (int k = 0; k < 8; k++) a[k] += v0 * b2f(h0[k]);
        }
    }

    // reduce across the 8 edge slots (lane bits 3..5)
#pragma unroll
    for (int k = 0; k < 8; k++) {
        a[k] += __shfl_xor(a[k], 8);
        a[k] += __shfl_xor(a[k], 16);
        a[k] += __shfl_xor(a[k], 32);
    }

    if (lane < 8) {
        float* op = out + (size_t)row * 256 + slice * 64 + lane * 8;
        float4 o0, o1;
        o0.x = fmaxf(a[0], 0.f); o0.y = fmaxf(a[1], 0.f);
        o0.z = fmaxf(a[2], 0.f); o0.w = fmaxf(a[3], 0.f);
        o1.x = fmaxf(a[4], 0.f); o1.y = fmaxf(a[5], 0.f);
        o1.z = fmaxf(a[6], 0.f); o1.w = fmaxf(a[7], 0.f);
        *(float4*)op       = o0;
        *(float4*)(op + 4) = o1;
    }
}

// ---------------------------------------------------------------------------
extern "C" void kernel_launch(void* const* d_in, const int* in_sizes, int n_in,
                              void* d_out, int out_size, void* d_ws, size_t ws_size,
                              hipStream_t stream) {
    const float* features = (const float*)d_in[0];
    const float* weight   = (const float*)d_in[1];
    const int*   adj_row  = (const int*)d_in[2];
    const int*   adj_col  = (const int*)d_in[3];
    const float* adj_val  = (const float*)d_in[4];
    float* out = (float*)d_out;

    char* ws = (char*)d_ws;
    size_t off = 0;
    auto alloc = [&](size_t bytes) -> char* {
        char* p = ws + off;
        off = (off + bytes + 255) & ~(size_t)255;
        return p;
    };
    unsigned short* sup     = (unsigned short*)alloc((size_t)N_NODES * 256 * 2);   // 51.2 MB
    unsigned short* BT      = (unsigned short*)alloc(256 * 256 * 2);
    int*            counts  = (int*)alloc((size_t)N_NODES * 4);
    int*            offsets = (int*)alloc((size_t)N_NODES * 4);
    unsigned int*   bucketK = (unsigned int*)alloc((size_t)N_EDGES * 4);           // 12.8 MB
    unsigned short* bucketV = (unsigned short*)alloc((size_t)N_EDGES * 2);         //  6.4 MB
    unsigned int*   runs    = (unsigned int*)alloc((size_t)NBUCK * NBLKE * 4);     //  1.2 MB
    unsigned int*   csr     = (unsigned int*)alloc((size_t)NBUCK * CAP_R * 4);     // 15.0 MB

    transpose_b<<<256, 256, 0, stream>>>(weight, BT);
    gemm_dma<<<782, 512, 0, stream>>>(features, BT, sup);          // ceil(100000/128)
    bin5_kernel<<<NBLKE, 512, 0, stream>>>(adj_row, adj_col, adj_val, bucketK, bucketV, runs);
    csort5_kernel<<<NBUCK, 1024, 0, stream>>>(bucketK, bucketV, runs, csr, offsets, counts);
    spmm_s4<<<100000, 256, 0, stream>>>(sup, offsets, counts, csr, out);
}